// Round 6
// baseline (378.788 us; speedup 1.0000x reference)
//
#include <hip/hip_runtime.h>
#include <stdint.h>

typedef __bf16 bf16;
typedef __bf16 bf16x8 __attribute__((ext_vector_type(8)));  // 16B
typedef __bf16 bf16x4 __attribute__((ext_vector_type(4)));  // 8B
typedef float  f32x4  __attribute__((ext_vector_type(4)));

#define MFMA_BF16(a, b, c) __builtin_amdgcn_mfma_f32_16x16x32_bf16((a), (b), (c), 0, 0, 0)

static constexpr int BATCH = 2;
static constexpr int SEQ   = 2048;
static constexpr int DIM   = 1024;
static constexpr int HDIM  = 64;
static constexpr int MROWS = BATCH * SEQ;   // 4096
static constexpr int NIN   = 11;
static constexpr int NWC   = 8;             // converted entries: inputs 3..10

// offsets of converted weights/biases inside conv region (elements)
static const long long W_OFF[NWC] = {
    0,        1048576,            // Wq, bq
    1049600,  2098176,            // Wk, bk
    2099200,  3147776,            // Wv, bv
    3148800,  4197376             // Wo, bo
};
static constexpr long long CONV_TOTAL = 4198400;

struct InPackAll { const void* p[NIN]; int n[NIN]; };
struct InPackW   { const void* p[NWC]; long long o[NWC]; int n[NWC]; int fi[NWC]; };

__device__ __forceinline__ float scrubf(float v) {
    unsigned b = __float_as_uint(v);
    return ((b & 0x7f800000u) == 0x7f800000u) ? 0.f : v;
}

typedef const __attribute__((address_space(1))) void* gvp;
typedef __attribute__((address_space(3))) void* svp;
__device__ __forceinline__ void glds16(const bf16* g, bf16* l) {
    __builtin_amdgcn_global_load_lds((gvp)(const void*)g, (svp)(void*)l, 16, 0, 0);
}

// ---------------------------------------------------------------------------
// dtype detection (fp32 vs bf16) per input buffer. flags[i]=1 -> fp32.
// ---------------------------------------------------------------------------
__global__ void detect_kernel(InPackAll in, int* __restrict__ flags) {
    const int i = blockIdx.x;
    const unsigned short* s = (const unsigned short*)in.p[i];
    const int scan = in.n[i] < 65536 ? in.n[i] : 65536;
    __shared__ int bad;
    if (threadIdx.x == 0) bad = 0;
    __syncthreads();
    int local = 0;
    for (int j = threadIdx.x; j < scan; j += 256) {
        const int e = (s[j] >> 7) & 0xFF;
        if (e >= 0x89) ++local;   // |x|>=1024 / inf / nan: impossible for true bf16 here
    }
    if (local) atomicAdd(&bad, local);
    __syncthreads();
    if (threadIdx.x == 0) flags[i] = (bad > 0) ? 1 : 0;
}

// ---------------------------------------------------------------------------
// Convert weights+biases (inputs 3..10) to clean bf16 in conv region.
// ---------------------------------------------------------------------------
__global__ void convert_kernel(InPackW in, bf16* __restrict__ dstbase,
                               const int* __restrict__ flags) {
    const int i = blockIdx.y;
    const int n4 = in.n[i] >> 2;
    bf16* dst = dstbase + in.o[i];
    const bool isf32 = (flags[in.fi[i]] != 0);
    for (int j = blockIdx.x * 256 + threadIdx.x; j < n4; j += gridDim.x * 256) {
        float v0, v1, v2, v3;
        if (isf32) {
            const float4 f = ((const float4*)in.p[i])[j];
            v0 = f.x; v1 = f.y; v2 = f.z; v3 = f.w;
        } else {
            const ushort4 u = ((const ushort4*)in.p[i])[j];
            v0 = __uint_as_float((unsigned)u.x << 16);
            v1 = __uint_as_float((unsigned)u.y << 16);
            v2 = __uint_as_float((unsigned)u.z << 16);
            v3 = __uint_as_float((unsigned)u.w << 16);
        }
        bf16x4 o = {(bf16)scrubf(v0), (bf16)scrubf(v1), (bf16)scrubf(v2), (bf16)scrubf(v3)};
        *(bf16x4*)&dst[(size_t)j * 4] = o;
    }
}

// ---------------------------------------------------------------------------
// QKV GEMM with fused A-dtype conversion: C = A @ W^T + bias, A = q/k/v raw
// input (fp32 or bf16 per flags[z]), W/bias pre-converted bf16, C bf16.
// 128x128 tile, BK=32. fp32 path: manual float4 load + cvt + ds_write_b128
// (same LDS addresses glds16 would produce); bf16 path: async glds16.
// ---------------------------------------------------------------------------
__global__ __launch_bounds__(256, 3) void gemm_qkv_kernel(
    const void* __restrict__ A0, const bf16* __restrict__ W0,
    const bf16* __restrict__ b0, bf16* __restrict__ C0,
    const void* __restrict__ A1, const bf16* __restrict__ W1,
    const bf16* __restrict__ b1, bf16* __restrict__ C1,
    const void* __restrict__ A2, const bf16* __restrict__ W2,
    const bf16* __restrict__ b2, bf16* __restrict__ C2,
    const int* __restrict__ flags)
{
    const int z = blockIdx.z;
    const void* A    = (z == 0) ? A0 : (z == 1) ? A1 : A2;
    const bf16* W    = (z == 0) ? W0 : (z == 1) ? W1 : W2;
    const bf16* bias = (z == 0) ? b0 : (z == 1) ? b1 : b2;
    bf16*       C    = (z == 0) ? C0 : (z == 1) ? C1 : C2;
    const bool af32  = flags[z] != 0;

    const int n0 = blockIdx.x * 128;
    const int m0 = blockIdx.y * 128;

    __shared__ bf16 As[128 * 32];
    __shared__ bf16 Bs[128 * 32];

    const int t    = threadIdx.x;
    const int w    = t >> 6;
    const int lane = t & 63;
    const int ln   = t & 15;
    const int quad = (t >> 4) & 3;
    const int wm   = (w & 1) * 64;
    const int wn   = (w >> 1) * 64;

    const int srow = w * 32 + (lane >> 2);
    const int scol = (lane & 3) * 8;
    const bf16*  gAb = (const bf16*)A + (size_t)(m0 + srow) * DIM + scol;
    const float* gAf = (const float*)A + (size_t)(m0 + srow) * DIM + scol;
    const bf16*  gB  = W + (size_t)(n0 + srow) * DIM + scol;
    bf16* lA = &As[w * 32 * 32];
    bf16* lB = &Bs[w * 32 * 32];
    bf16* lAme = lA + lane * 8;      // manual-path per-lane target (== glds16 dest)

    f32x4 acc[4][4];
#pragma unroll
    for (int i = 0; i < 4; ++i)
#pragma unroll
        for (int j = 0; j < 4; ++j) acc[i][j] = (f32x4){0.f, 0.f, 0.f, 0.f};

    for (int k0 = 0; k0 < DIM; k0 += 32) {
        __syncthreads();
        if (af32) {
            const float4 x0 = *(const float4*)(gAf + k0);
            const float4 x1 = *(const float4*)(gAf + k0 + 4);
            const float4 y0 = *(const float4*)(gAf + 16 * DIM + k0);
            const float4 y1 = *(const float4*)(gAf + 16 * DIM + k0 + 4);
            bf16x8 r0 = {(bf16)x0.x, (bf16)x0.y, (bf16)x0.z, (bf16)x0.w,
                         (bf16)x1.x, (bf16)x1.y, (bf16)x1.z, (bf16)x1.w};
            bf16x8 r1 = {(bf16)y0.x, (bf16)y0.y, (bf16)y0.z, (bf16)y0.w,
                         (bf16)y1.x, (bf16)y1.y, (bf16)y1.z, (bf16)y1.w};
            *(bf16x8*)lAme            = r0;
            *(bf16x8*)(lAme + 16 * 32) = r1;
        } else {
            glds16(gAb + k0,            lA);
            glds16(gAb + 16 * DIM + k0, lA + 16 * 32);
        }
        glds16(gB + k0,            lB);
        glds16(gB + 16 * DIM + k0, lB + 16 * 32);
        __syncthreads();

        bf16x8 af[4], bfr[4];
#pragma unroll
        for (int mt = 0; mt < 4; ++mt)
            af[mt] = *(const bf16x8*)&As[(wm + mt * 16 + ln) * 32 + quad * 8];
#pragma unroll
        for (int nt = 0; nt < 4; ++nt)
            bfr[nt] = *(const bf16x8*)&Bs[(wn + nt * 16 + ln) * 32 + quad * 8];
#pragma unroll
        for (int mt = 0; mt < 4; ++mt)
#pragma unroll
            for (int nt = 0; nt < 4; ++nt)
                acc[mt][nt] = MFMA_BF16(af[mt], bfr[nt], acc[mt][nt]);
    }

#pragma unroll
    for (int nt = 0; nt < 4; ++nt) {
        const int col  = n0 + wn + nt * 16 + ln;
        const float bv = (float)bias[col];
#pragma unroll
        for (int mt = 0; mt < 4; ++mt)
#pragma unroll
            for (int r = 0; r < 4; ++r) {
                const int row = m0 + wm + mt * 16 + quad * 4 + r;
                C[(size_t)row * DIM + col] = (bf16)(acc[mt][nt][r] + bv);
            }
    }
}

// ---------------------------------------------------------------------------
// Output GEMM: C = A @ Wo^T + bo, A bf16 (merge output), C dtype per flags[0].
// ---------------------------------------------------------------------------
__global__ __launch_bounds__(256, 3) void gemm_out_kernel(
    const bf16* __restrict__ A, const bf16* __restrict__ W,
    const bf16* __restrict__ bias, void* __restrict__ C,
    const int* __restrict__ flags)
{
    const bool of32 = flags[0] != 0;
    const int n0 = blockIdx.x * 128;
    const int m0 = blockIdx.y * 128;

    __shared__ bf16 As[128 * 32];
    __shared__ bf16 Bs[128 * 32];

    const int t    = threadIdx.x;
    const int w    = t >> 6;
    const int lane = t & 63;
    const int ln   = t & 15;
    const int quad = (t >> 4) & 3;
    const int wm   = (w & 1) * 64;
    const int wn   = (w >> 1) * 64;

    const int srow = w * 32 + (lane >> 2);
    const int scol = (lane & 3) * 8;
    const bf16* gA = A + (size_t)(m0 + srow) * DIM + scol;
    const bf16* gB = W + (size_t)(n0 + srow) * DIM + scol;
    bf16* lA = &As[w * 32 * 32];
    bf16* lB = &Bs[w * 32 * 32];

    f32x4 acc[4][4];
#pragma unroll
    for (int i = 0; i < 4; ++i)
#pragma unroll
        for (int j = 0; j < 4; ++j) acc[i][j] = (f32x4){0.f, 0.f, 0.f, 0.f};

    for (int k0 = 0; k0 < DIM; k0 += 32) {
        __syncthreads();
        glds16(gA + k0,            lA);
        glds16(gA + 16 * DIM + k0, lA + 16 * 32);
        glds16(gB + k0,            lB);
        glds16(gB + 16 * DIM + k0, lB + 16 * 32);
        __syncthreads();

        bf16x8 af[4], bfr[4];
#pragma unroll
        for (int mt = 0; mt < 4; ++mt)
            af[mt] = *(const bf16x8*)&As[(wm + mt * 16 + ln) * 32 + quad * 8];
#pragma unroll
        for (int nt = 0; nt < 4; ++nt)
            bfr[nt] = *(const bf16x8*)&Bs[(wn + nt * 16 + ln) * 32 + quad * 8];
#pragma unroll
        for (int mt = 0; mt < 4; ++mt)
#pragma unroll
            for (int nt = 0; nt < 4; ++nt)
                acc[mt][nt] = MFMA_BF16(af[mt], bfr[nt], acc[mt][nt]);
    }

    if (of32) {
        float* Cf = (float*)C;
#pragma unroll
        for (int nt = 0; nt < 4; ++nt) {
            const int col  = n0 + wn + nt * 16 + ln;
            const float bv = (float)bias[col];
#pragma unroll
            for (int mt = 0; mt < 4; ++mt)
#pragma unroll
                for (int r = 0; r < 4; ++r) {
                    const int row = m0 + wm + mt * 16 + quad * 4 + r;
                    Cf[(size_t)row * DIM + col] = acc[mt][nt][r] + bv;
                }
        }
    } else {
        bf16* Cb = (bf16*)C;
#pragma unroll
        for (int nt = 0; nt < 4; ++nt) {
            const int col  = n0 + wn + nt * 16 + ln;
            const float bv = (float)bias[col];
#pragma unroll
            for (int mt = 0; mt < 4; ++mt)
#pragma unroll
                for (int r = 0; r < 4; ++r) {
                    const int row = m0 + wm + mt * 16 + quad * 4 + r;
                    Cb[(size_t)row * DIM + col] = (bf16)(acc[mt][nt][r] + bv);
                }
        }
    }
}

// ---------------------------------------------------------------------------
// Flash attention, S^T formulation, BQ=128, SPLIT-K=2: blockIdx.z = k-half.
// Each block does 8 k-iters over its half; stores fp32 partial O (no div)
// plus per-q-row (m, l) in log2 domain. Merge kernel combines halves.
// ---------------------------------------------------------------------------
__global__ __launch_bounds__(256, 3) void attn_kernel(
    const bf16* __restrict__ Q, const bf16* __restrict__ K,
    const bf16* __restrict__ V, float* __restrict__ Opart,
    float* __restrict__ Mp, float* __restrict__ Lp)
{
    const int qt = blockIdx.x;        // 0..15: 128 q-rows
    const int bh = blockIdx.y;        // 0..31
    const int kh = blockIdx.z;        // 0..1: k-half
    const int b  = bh >> 4;
    const int h  = bh & 15;

    __shared__ bf16 Ks[128 * 72];
    __shared__ bf16 Vt[64 * 136];
    __shared__ bf16 Ps[64 * 136];

    const int t    = threadIdx.x;
    const int w    = t >> 6;
    const int lane = t & 63;
    const int ln   = lane & 15;
    const int quad = lane >> 4;

    const int q0 = qt * 128;

    const float sc = 0.125f * 1.44269504089f;
    bf16x8 qf[2][2];
#pragma unroll
    for (int g = 0; g < 2; ++g) {
        const bf16* qrow = Q + (size_t)(b * SEQ + q0 + w * 32 + g * 16 + ln) * DIM + h * HDIM;
        qf[g][0] = *(const bf16x8*)(qrow + quad * 8);
        qf[g][1] = *(const bf16x8*)(qrow + 32 + quad * 8);
#pragma unroll
        for (int i = 0; i < 8; ++i) {
            qf[g][0][i] = (bf16)((float)qf[g][0][i] * sc);
            qf[g][1][i] = (bf16)((float)qf[g][1][i] * sc);
        }
    }

    f32x4 o_acc[2][4];
#pragma unroll
    for (int g = 0; g < 2; ++g)
#pragma unroll
        for (int c = 0; c < 4; ++c) o_acc[g][c] = (f32x4){0.f, 0.f, 0.f, 0.f};
    float m_s[2] = {-1e30f, -1e30f};
    float l_s[2] = {0.f, 0.f};

    const int krow = t >> 3;
    const int kcol = (t & 7) * 8;
    const int vrq  = t >> 3;
    const int va   = t & 7;
    const int psrow = (w * 16 + ln) * 136;

    const int kbeg = kh * (SEQ / 2);
    for (int kb = kbeg; kb < kbeg + SEQ / 2; kb += 128) {
        __syncthreads();
#pragma unroll
        for (int i = 0; i < 4; ++i) {
            const int r = krow + i * 32;
            *(bf16x8*)&Ks[r * 72 + kcol] =
                *(const bf16x8*)(K + (size_t)(b * SEQ + kb + r) * DIM + h * HDIM + kcol);
        }
        {
            bf16x8 vrow[4];
            const bf16* vbase = V + (size_t)(b * SEQ + kb + vrq * 4) * DIM + h * HDIM + va * 8;
#pragma unroll
            for (int i = 0; i < 4; ++i)
                vrow[i] = *(const bf16x8*)(vbase + (size_t)i * DIM);
            const int phys = ((vrq >> 1) ^ va) * 8 + (vrq & 1) * 4;
#pragma unroll
            for (int j = 0; j < 8; ++j) {
                bf16x4 pk = {vrow[0][j], vrow[1][j], vrow[2][j], vrow[3][j]};
                *(bf16x4*)&Vt[(va * 8 + j) * 136 + phys] = pk;
            }
        }
        __syncthreads();

        f32x4 sa0[8], sa1[8];
#pragma unroll
        for (int nt = 0; nt < 8; ++nt) {
            const bf16x8 kf0 = *(const bf16x8*)&Ks[(nt * 16 + ln) * 72 + quad * 8];
            const bf16x8 kf1 = *(const bf16x8*)&Ks[(nt * 16 + ln) * 72 + 32 + quad * 8];
            f32x4 z0 = (f32x4){0.f, 0.f, 0.f, 0.f};
            z0 = MFMA_BF16(kf0, qf[0][0], z0);
            z0 = MFMA_BF16(kf1, qf[0][1], z0);
            sa0[nt] = z0;
            f32x4 z1 = (f32x4){0.f, 0.f, 0.f, 0.f};
            z1 = MFMA_BF16(kf0, qf[1][0], z1);
            z1 = MFMA_BF16(kf1, qf[1][1], z1);
            sa1[nt] = z1;
        }

        float al[2];
#pragma unroll
        for (int g = 0; g < 2; ++g) {
            f32x4* sa = g ? sa1 : sa0;
            float mx = -1e30f;
#pragma unroll
            for (int nt = 0; nt < 8; ++nt)
#pragma unroll
                for (int r = 0; r < 4; ++r) mx = fmaxf(mx, sa[nt][r]);
            mx = fmaxf(mx, __shfl_xor(mx, 16));
            mx = fmaxf(mx, __shfl_xor(mx, 32));
            const float mn = fmaxf(m_s[g], mx);
            al[g] = exp2f(m_s[g] - mn);
            m_s[g] = mn;
            float rs = 0.f;
#pragma unroll
            for (int nt = 0; nt < 8; ++nt)
#pragma unroll
                for (int r = 0; r < 4; ++r) {
                    const float p = exp2f(sa[nt][r] - mn);
                    sa[nt][r] = p;
                    rs += p;
                }
            rs += __shfl_xor(rs, 16);
            rs += __shfl_xor(rs, 32);
            l_s[g] = l_s[g] * al[g] + rs;
#pragma unroll
            for (int r = 0; r < 4; ++r) {
                const float alr = __shfl(al[g], quad * 4 + r);
#pragma unroll
                for (int c = 0; c < 4; ++c) o_acc[g][c][r] *= alr;
            }
        }

#pragma unroll
        for (int nt = 0; nt < 8; ++nt) {
            bf16x4 pk = {(bf16)sa0[nt][0], (bf16)sa0[nt][1],
                         (bf16)sa0[nt][2], (bf16)sa0[nt][3]};
            *(bf16x4*)&Ps[psrow + nt * 16 + quad * 4] = pk;
        }
        __asm__ volatile("s_waitcnt lgkmcnt(0)" ::: "memory");
        bf16x8 pf0[4];
#pragma unroll
        for (int kc = 0; kc < 4; ++kc)
            pf0[kc] = *(const bf16x8*)&Ps[psrow + kc * 32 + quad * 8];
        __asm__ volatile("s_waitcnt lgkmcnt(0)" ::: "memory");
#pragma unroll
        for (int nt = 0; nt < 8; ++nt) {
            bf16x4 pk = {(bf16)sa1[nt][0], (bf16)sa1[nt][1],
                         (bf16)sa1[nt][2], (bf16)sa1[nt][3]};
            *(bf16x4*)&Ps[psrow + nt * 16 + quad * 4] = pk;
        }
        bf16x8 vf[4][4];
#pragma unroll
        for (int kc = 0; kc < 4; ++kc)
#pragma unroll
            for (int c = 0; c < 4; ++c) {
                const int e = c * 16 + ln;
                const int phys = (kc * 4 + quad) ^ (e >> 3);
                vf[kc][c] = *(const bf16x8*)&Vt[e * 136 + phys * 8];
            }
        __asm__ volatile("s_waitcnt lgkmcnt(0)" ::: "memory");

#pragma unroll
        for (int kc = 0; kc < 4; ++kc)
#pragma unroll
            for (int c = 0; c < 4; ++c)
                o_acc[0][c] = MFMA_BF16(pf0[kc], vf[kc][c], o_acc[0][c]);
        bf16x8 pf1[4];
#pragma unroll
        for (int kc = 0; kc < 4; ++kc)
            pf1[kc] = *(const bf16x8*)&Ps[psrow + kc * 32 + quad * 8];
        __asm__ volatile("s_waitcnt lgkmcnt(0)" ::: "memory");
#pragma unroll
        for (int kc = 0; kc < 4; ++kc)
#pragma unroll
            for (int c = 0; c < 4; ++c)
                o_acc[1][c] = MFMA_BF16(pf1[kc], vf[kc][c], o_acc[1][c]);
    }

    // ---- epilogue: fp32 partials (no normalization) + (m,l)
    const size_t obase = (size_t)kh * MROWS * DIM;
#pragma unroll
    for (int g = 0; g < 2; ++g) {
#pragma unroll
        for (int r = 0; r < 4; ++r) {
            const size_t rowoff = obase +
                (size_t)(b * SEQ + q0 + w * 32 + g * 16 + quad * 4 + r) * DIM + h * HDIM;
#pragma unroll
            for (int c = 0; c < 4; ++c)
                Opart[rowoff + c * 16 + ln] = o_acc[g][c][r];
        }
    }
    if (quad == 0) {
#pragma unroll
        for (int g = 0; g < 2; ++g) {
            const size_t idx = (size_t)kh * (BATCH * 16 * SEQ) +
                (size_t)((b << 4) + h) * SEQ + q0 + w * 32 + g * 16 + ln;
            Mp[idx] = m_s[g];
            Lp[idx] = l_s[g];
        }
    }
}

// ---------------------------------------------------------------------------
// Merge the two k-halves: O = (O0*2^(m0-m*) + O1*2^(m1-m*)) / (l0*w0 + l1*w1)
// ---------------------------------------------------------------------------
__global__ void merge_kernel(const float* __restrict__ Op, const float* __restrict__ Mp,
                             const float* __restrict__ Lp, bf16* __restrict__ Ob) {
    const int j4 = blockIdx.x * 256 + threadIdx.x;   // exactly MROWS*DIM/4 threads
    const int j  = j4 << 2;
    const int row = j >> 10;
    const int col = j & 1023;
    const int b = row >> 11, s = row & 2047;
    const int h = col >> 6;
    const int mli = ((b << 4) + h) * SEQ + s;
    const float m0 = Mp[mli], m1 = Mp[BATCH * 16 * SEQ + mli];
    const float l0 = Lp[mli], l1 = Lp[BATCH * 16 * SEQ + mli];
    const float mx = fmaxf(m0, m1);
    const float w0 = exp2f(m0 - mx), w1 = exp2f(m1 - mx);
    const float inv = 1.0f / (l0 * w0 + l1 * w1);
    const float4 a = *(const float4*)&Op[(size_t)row * DIM + col];
    const float4 c = *(const float4*)&Op[(size_t)MROWS * DIM + (size_t)row * DIM + col];
    bf16x4 o = {(bf16)((a.x * w0 + c.x * w1) * inv),
                (bf16)((a.y * w0 + c.y * w1) * inv),
                (bf16)((a.z * w0 + c.z * w1) * inv),
                (bf16)((a.w * w0 + c.w * w1) * inv)};
    *(bf16x4*)&Ob[(size_t)row * DIM + col] = o;
}

extern "C" void kernel_launch(void* const* d_in, const int* in_sizes, int n_in,
                              void* d_out, int out_size, void* d_ws, size_t ws_size,
                              hipStream_t stream) {
    // ws layout (bytes):
    //   Qb,Kb,Vb,Ob  bf16  4 x 8,388,608         [0 .. 33,554,432)
    //   conv         bf16  8,396,800             [33,554,432 .. 41,951,232)
    //   Opart        fp32  33,554,432            [41,951,232 .. 75,505,664)
    //   Mp, Lp       fp32  2 x 524,288           [.. 76,554,240)
    //   flags        int[11]
    bf16*  Qb    = (bf16*)d_ws;
    bf16*  Kb    = Qb + (size_t)MROWS * DIM;
    bf16*  Vb    = Kb + (size_t)MROWS * DIM;
    bf16*  Ob    = Vb + (size_t)MROWS * DIM;
    bf16*  conv  = Ob + (size_t)MROWS * DIM;
    float* Opart = (float*)((char*)d_ws + 41951232);
    float* Mp    = (float*)((char*)d_ws + 75505664);
    float* Lp    = (float*)((char*)d_ws + 76029952);
    int*   flags = (int*)((char*)d_ws + 76554240);

    InPackAll packA;
    for (int i = 0; i < NIN; ++i) { packA.p[i] = d_in[i]; packA.n[i] = in_sizes[i]; }

    InPackW packW;
    for (int i = 0; i < NWC; ++i) {
        packW.p[i]  = d_in[3 + i];
        packW.o[i]  = W_OFF[i];
        packW.n[i]  = in_sizes[3 + i];
        packW.fi[i] = 3 + i;
    }

    detect_kernel<<<NIN, 256, 0, stream>>>(packA, flags);
    convert_kernel<<<dim3(1024, NWC), 256, 0, stream>>>(packW, conv, flags);

    const bf16* Wqc = conv + W_OFF[0];
    const bf16* bqc = conv + W_OFF[1];
    const bf16* Wkc = conv + W_OFF[2];
    const bf16* bkc = conv + W_OFF[3];
    const bf16* Wvc = conv + W_OFF[4];
    const bf16* bvc = conv + W_OFF[5];
    const bf16* Woc = conv + W_OFF[6];
    const bf16* boc = conv + W_OFF[7];

    gemm_qkv_kernel<<<dim3(DIM / 128, MROWS / 128, 3), 256, 0, stream>>>(
        d_in[0], Wqc, bqc, Qb,
        d_in[1], Wkc, bkc, Kb,
        d_in[2], Wvc, bvc, Vb, flags);

    attn_kernel<<<dim3(SEQ / 128, BATCH * 16, 2), 256, 0, stream>>>(
        Qb, Kb, Vb, Opart, Mp, Lp);

    merge_kernel<<<(MROWS * DIM / 4) / 256, 256, 0, stream>>>(Opart, Mp, Lp, Ob);

    gemm_out_kernel<<<dim3(DIM / 128, MROWS / 128), 256, 0, stream>>>(
        Ob, Woc, boc, d_out, flags);
}

// Round 7
// 291.947 us; speedup vs baseline: 1.2975x; 1.2975x over previous
//
#include <hip/hip_runtime.h>
#include <stdint.h>

typedef __bf16 bf16;
typedef __bf16 bf16x8 __attribute__((ext_vector_type(8)));  // 16B
typedef __bf16 bf16x4 __attribute__((ext_vector_type(4)));  // 8B
typedef float  f32x4  __attribute__((ext_vector_type(4)));

#define MFMA_BF16(a, b, c) __builtin_amdgcn_mfma_f32_16x16x32_bf16((a), (b), (c), 0, 0, 0)

static constexpr int BATCH = 2;
static constexpr int SEQ   = 2048;
static constexpr int DIM   = 1024;
static constexpr int HDIM  = 64;
static constexpr int MROWS = BATCH * SEQ;   // 4096

typedef const __attribute__((address_space(1))) void* gvp;
typedef __attribute__((address_space(3))) void* svp;
__device__ __forceinline__ void glds16(const bf16* g, bf16* l) {
    __builtin_amdgcn_global_load_lds((gvp)(const void*)g, (svp)(void*)l, 16, 0, 0);
}

// scan leading nscan u16 of buffer as bf16; any exponent>=0x89 (|x|>=1024 /
// inf / nan) -> fp32 data misread as bf16 (P~0.46 per elem; deterministic
// across blocks since all scan identical bytes). True bf16 here has |x|<6.
__device__ __forceinline__ int scan_f32(const void* p, int nscan, int t) {
    const unsigned short* s = (const unsigned short*)p;
    int local = 0;
    for (int j = t; j < nscan; j += 256)
        local |= (((s[j] >> 7) & 0xFF) >= 0x89) ? 1 : 0;
    return local;
}

__device__ __forceinline__ bf16x8 cvt8(const float4 a, const float4 b) {
    bf16x8 r = {(bf16)a.x, (bf16)a.y, (bf16)a.z, (bf16)a.w,
                (bf16)b.x, (bf16)b.y, (bf16)b.z, (bf16)b.w};
    return r;
}

// ---------------------------------------------------------------------------
// QKV GEMM, dtype-adaptive: C = A @ W^T + bias. A/W/bias raw inputs (fp32 or
// bf16, block-self-detected). 128x128 tile, BK=32. fp32 operands use a
// register-prefetch pipeline (load k+32 during k's MFMAs) + ds_write_b128;
// bf16 operands use async glds16. z==2 (V) stores C transposed per head:
// Vt_g[b][h][e][s], vectorized bf16x4 along s.
// ---------------------------------------------------------------------------
__global__ __launch_bounds__(256, 3) void gemm_qkv_kernel(
    const void* __restrict__ A0, const void* __restrict__ W0,
    const void* __restrict__ b0, bf16* __restrict__ C0,
    const void* __restrict__ A1, const void* __restrict__ W1,
    const void* __restrict__ b1, bf16* __restrict__ C1,
    const void* __restrict__ A2, const void* __restrict__ W2,
    const void* __restrict__ b2, bf16* __restrict__ Vtg,
    int* __restrict__ flagsOut)
{
    const int z = blockIdx.z;
    const void* A  = (z == 0) ? A0 : (z == 1) ? A1 : A2;
    const void* W  = (z == 0) ? W0 : (z == 1) ? W1 : W2;
    const void* bi = (z == 0) ? b0 : (z == 1) ? b1 : b2;

    __shared__ int sbad;
    __shared__ bf16 As[128 * 32];
    __shared__ bf16 Bs[128 * 32];

    const int t = threadIdx.x;
    if (t == 0) sbad = 0;
    __syncthreads();
    int loc = scan_f32(A, 4096, t) | (scan_f32(W, 4096, t) << 1) |
              (scan_f32(bi, 1024, t) << 2);
    if (loc) atomicOr(&sbad, loc);
    __syncthreads();
    const bool af32 = sbad & 1, wf32 = sbad & 2, bf32 = sbad & 4;
    if (z == 0 && blockIdx.x == 0 && blockIdx.y == 0 && t == 0)
        flagsOut[0] = af32 ? 1 : 0;

    const int n0 = blockIdx.x * 128;
    const int m0 = blockIdx.y * 128;
    const int w    = t >> 6;
    const int lane = t & 63;
    const int ln   = t & 15;
    const int quad = (t >> 4) & 3;
    const int wm   = (w & 1) * 64;
    const int wn   = (w >> 1) * 64;

    const int srow = w * 32 + (lane >> 2);
    const int scol = (lane & 3) * 8;
    const bf16*  gAb = (const bf16*)A  + (size_t)(m0 + srow) * DIM + scol;
    const float* gAf = (const float*)A + (size_t)(m0 + srow) * DIM + scol;
    const bf16*  gWb = (const bf16*)W  + (size_t)(n0 + srow) * DIM + scol;
    const float* gWf = (const float*)W + (size_t)(n0 + srow) * DIM + scol;
    bf16* lA = &As[w * 32 * 32];
    bf16* lW = &Bs[w * 32 * 32];
    bf16* lAme = lA + lane * 8;
    bf16* lWme = lW + lane * 8;

    float4 pa[4], pw[4];
    if (af32) {
        pa[0] = *(const float4*)(gAf);     pa[1] = *(const float4*)(gAf + 4);
        pa[2] = *(const float4*)(gAf + 16 * DIM); pa[3] = *(const float4*)(gAf + 16 * DIM + 4);
    }
    if (wf32) {
        pw[0] = *(const float4*)(gWf);     pw[1] = *(const float4*)(gWf + 4);
        pw[2] = *(const float4*)(gWf + 16 * DIM); pw[3] = *(const float4*)(gWf + 16 * DIM + 4);
    }

    f32x4 acc[4][4];
#pragma unroll
    for (int i = 0; i < 4; ++i)
#pragma unroll
        for (int j = 0; j < 4; ++j) acc[i][j] = (f32x4){0.f, 0.f, 0.f, 0.f};

    for (int k0 = 0; k0 < DIM; k0 += 32) {
        __syncthreads();
        if (af32) {
            *(bf16x8*)lAme             = cvt8(pa[0], pa[1]);
            *(bf16x8*)(lAme + 16 * 32) = cvt8(pa[2], pa[3]);
        } else {
            glds16(gAb + k0,            lA);
            glds16(gAb + 16 * DIM + k0, lA + 16 * 32);
        }
        if (wf32) {
            *(bf16x8*)lWme             = cvt8(pw[0], pw[1]);
            *(bf16x8*)(lWme + 16 * 32) = cvt8(pw[2], pw[3]);
        } else {
            glds16(gWb + k0,            lW);
            glds16(gWb + 16 * DIM + k0, lW + 16 * 32);
        }
        const int kn = (k0 + 32 < DIM) ? k0 + 32 : 0;   // dummy reload on last iter
        if (af32) {
            pa[0] = *(const float4*)(gAf + kn);     pa[1] = *(const float4*)(gAf + kn + 4);
            pa[2] = *(const float4*)(gAf + 16 * DIM + kn); pa[3] = *(const float4*)(gAf + 16 * DIM + kn + 4);
        }
        if (wf32) {
            pw[0] = *(const float4*)(gWf + kn);     pw[1] = *(const float4*)(gWf + kn + 4);
            pw[2] = *(const float4*)(gWf + 16 * DIM + kn); pw[3] = *(const float4*)(gWf + 16 * DIM + kn + 4);
        }
        __syncthreads();

        bf16x8 af[4], bfr[4];
#pragma unroll
        for (int mt = 0; mt < 4; ++mt)
            af[mt] = *(const bf16x8*)&As[(wm + mt * 16 + ln) * 32 + quad * 8];
#pragma unroll
        for (int nt = 0; nt < 4; ++nt)
            bfr[nt] = *(const bf16x8*)&Bs[(wn + nt * 16 + ln) * 32 + quad * 8];
#pragma unroll
        for (int mt = 0; mt < 4; ++mt)
#pragma unroll
            for (int nt = 0; nt < 4; ++nt)
                acc[mt][nt] = MFMA_BF16(af[mt], bfr[nt], acc[mt][nt]);
    }

    if (z == 2) {
        // V epilogue: store transposed per head -> Vt_g[((b*16+h)*64+e)*SEQ + s]
#pragma unroll
        for (int nt = 0; nt < 4; ++nt) {
            const int col = n0 + wn + nt * 16 + ln;       // d
            const int h2 = col >> 6, e = col & 63;
            const float bv = bf32 ? ((const float*)bi)[col]
                                  : (float)(((const bf16*)bi)[col]);
#pragma unroll
            for (int mt = 0; mt < 4; ++mt) {
                const int row = m0 + wm + mt * 16 + quad * 4;
                const int bb = row >> 11, s = row & 2047;
                bf16x4 o = {(bf16)(acc[mt][nt][0] + bv), (bf16)(acc[mt][nt][1] + bv),
                            (bf16)(acc[mt][nt][2] + bv), (bf16)(acc[mt][nt][3] + bv)};
                *(bf16x4*)&Vtg[((size_t)((bb * 16 + h2) * 64 + e)) * SEQ + s] = o;
            }
        }
    } else {
        bf16* C = (z == 0) ? C0 : C1;
#pragma unroll
        for (int nt = 0; nt < 4; ++nt) {
            const int col = n0 + wn + nt * 16 + ln;
            const float bv = bf32 ? ((const float*)bi)[col]
                                  : (float)(((const bf16*)bi)[col]);
#pragma unroll
            for (int mt = 0; mt < 4; ++mt)
#pragma unroll
                for (int r = 0; r < 4; ++r) {
                    const int row = m0 + wm + mt * 16 + quad * 4 + r;
                    C[(size_t)row * DIM + col] = (bf16)(acc[mt][nt][r] + bv);
                }
        }
    }
}

// ---------------------------------------------------------------------------
// Output GEMM: C = A @ Wo^T + bo. A bf16 (attn output, glds16), Wo/bo raw
// (self-detected), C dtype per flags[0] (written by gemm_qkv).
// ---------------------------------------------------------------------------
__global__ __launch_bounds__(256, 3) void gemm_out_kernel(
    const bf16* __restrict__ A, const void* __restrict__ W,
    const void* __restrict__ bi, void* __restrict__ C,
    const int* __restrict__ flags)
{
    __shared__ int sbad;
    __shared__ bf16 As[128 * 32];
    __shared__ bf16 Bs[128 * 32];

    const int t = threadIdx.x;
    if (t == 0) sbad = 0;
    __syncthreads();
    int loc = (scan_f32(W, 4096, t) << 1) | (scan_f32(bi, 1024, t) << 2);
    if (loc) atomicOr(&sbad, loc);
    __syncthreads();
    const bool wf32 = sbad & 2, bf32 = sbad & 4;
    const bool of32 = flags[0] != 0;

    const int n0 = blockIdx.x * 128;
    const int m0 = blockIdx.y * 128;
    const int w    = t >> 6;
    const int lane = t & 63;
    const int ln   = t & 15;
    const int quad = (t >> 4) & 3;
    const int wm   = (w & 1) * 64;
    const int wn   = (w >> 1) * 64;

    const int srow = w * 32 + (lane >> 2);
    const int scol = (lane & 3) * 8;
    const bf16*  gA  = A + (size_t)(m0 + srow) * DIM + scol;
    const bf16*  gWb = (const bf16*)W  + (size_t)(n0 + srow) * DIM + scol;
    const float* gWf = (const float*)W + (size_t)(n0 + srow) * DIM + scol;
    bf16* lA = &As[w * 32 * 32];
    bf16* lW = &Bs[w * 32 * 32];
    bf16* lWme = lW + lane * 8;

    float4 pw[4];
    if (wf32) {
        pw[0] = *(const float4*)(gWf);     pw[1] = *(const float4*)(gWf + 4);
        pw[2] = *(const float4*)(gWf + 16 * DIM); pw[3] = *(const float4*)(gWf + 16 * DIM + 4);
    }

    f32x4 acc[4][4];
#pragma unroll
    for (int i = 0; i < 4; ++i)
#pragma unroll
        for (int j = 0; j < 4; ++j) acc[i][j] = (f32x4){0.f, 0.f, 0.f, 0.f};

    for (int k0 = 0; k0 < DIM; k0 += 32) {
        __syncthreads();
        glds16(gA + k0,            lA);
        glds16(gA + 16 * DIM + k0, lA + 16 * 32);
        if (wf32) {
            *(bf16x8*)lWme             = cvt8(pw[0], pw[1]);
            *(bf16x8*)(lWme + 16 * 32) = cvt8(pw[2], pw[3]);
        } else {
            glds16(gWb + k0,            lW);
            glds16(gWb + 16 * DIM + k0, lW + 16 * 32);
        }
        const int kn = (k0 + 32 < DIM) ? k0 + 32 : 0;
        if (wf32) {
            pw[0] = *(const float4*)(gWf + kn);     pw[1] = *(const float4*)(gWf + kn + 4);
            pw[2] = *(const float4*)(gWf + 16 * DIM + kn); pw[3] = *(const float4*)(gWf + 16 * DIM + kn + 4);
        }
        __syncthreads();

        bf16x8 af[4], bfr[4];
#pragma unroll
        for (int mt = 0; mt < 4; ++mt)
            af[mt] = *(const bf16x8*)&As[(wm + mt * 16 + ln) * 32 + quad * 8];
#pragma unroll
        for (int nt = 0; nt < 4; ++nt)
            bfr[nt] = *(const bf16x8*)&Bs[(wn + nt * 16 + ln) * 32 + quad * 8];
#pragma unroll
        for (int mt = 0; mt < 4; ++mt)
#pragma unroll
            for (int nt = 0; nt < 4; ++nt)
                acc[mt][nt] = MFMA_BF16(af[mt], bfr[nt], acc[mt][nt]);
    }

#pragma unroll
    for (int nt = 0; nt < 4; ++nt) {
        const int col = n0 + wn + nt * 16 + ln;
        const float bv = bf32 ? ((const float*)bi)[col]
                              : (float)(((const bf16*)bi)[col]);
#pragma unroll
        for (int mt = 0; mt < 4; ++mt)
#pragma unroll
            for (int r = 0; r < 4; ++r) {
                const int row = m0 + wm + mt * 16 + quad * 4 + r;
                if (of32) ((float*)C)[(size_t)row * DIM + col] = acc[mt][nt][r] + bv;
                else      ((bf16*)C)[(size_t)row * DIM + col] = (bf16)(acc[mt][nt][r] + bv);
            }
    }
}

// ---------------------------------------------------------------------------
// Flash attention, S^T formulation, BQ=128, single-K (split-K reverted).
// K and V^T tiles staged fully async via glds16 with SOURCE-SIDE XOR-chunk
// swizzles (LDS dest is rigid base+lane*16; the swizzle permutes which global
// chunk each lane fetches):
//   Ks[r][e]: byte(r,c) = r*128 + (c^(r&7))*16   -> kf reads spread even
//   Vt[e][k]: byte(e,c) = e*256 + (c^(e&15))*16  -> vf reads spread even
// V comes pre-transposed from gemm_qkv (Vt_g[b][h][e][s]). Zero VALU staging.
// ---------------------------------------------------------------------------
__global__ __launch_bounds__(256, 2) void attn_kernel(
    const bf16* __restrict__ Q, const bf16* __restrict__ K,
    const bf16* __restrict__ Vtg, bf16* __restrict__ O)
{
    const int qt = blockIdx.x;        // 0..15: 128 q-rows
    const int bh = blockIdx.y;        // 0..31
    const int b  = bh >> 4;
    const int h  = bh & 15;

    __shared__ bf16 Ks[128 * 64];     // swizzled, stride 64
    __shared__ bf16 Vt[64 * 128];     // swizzled, stride 128
    __shared__ bf16 Ps[64 * 136];     // padded 136 (as R5)

    const int t    = threadIdx.x;
    const int w    = t >> 6;
    const int lane = t & 63;
    const int ln   = lane & 15;
    const int quad = lane >> 4;

    const int q0 = qt * 128;

    const float sc = 0.125f * 1.44269504089f;   // 1/sqrt(HD) * log2(e)
    bf16x8 qf[2][2];
#pragma unroll
    for (int g = 0; g < 2; ++g) {
        const bf16* qrow = Q + (size_t)(b * SEQ + q0 + w * 32 + g * 16 + ln) * DIM + h * HDIM;
        qf[g][0] = *(const bf16x8*)(qrow + quad * 8);
        qf[g][1] = *(const bf16x8*)(qrow + 32 + quad * 8);
#pragma unroll
        for (int i = 0; i < 8; ++i) {
            qf[g][0][i] = (bf16)((float)qf[g][0][i] * sc);
            qf[g][1][i] = (bf16)((float)qf[g][1][i] * sc);
        }
    }

    f32x4 o_acc[2][4];
#pragma unroll
    for (int g = 0; g < 2; ++g)
#pragma unroll
        for (int c = 0; c < 4; ++c) o_acc[g][c] = (f32x4){0.f, 0.f, 0.f, 0.f};
    float m_s[2] = {-1e30f, -1e30f};
    float l_s[2] = {0.f, 0.f};

    // K staging: wave w, instr i stages rows w*32+i*8 .. +7 (8 rows x 8 chunks)
    const int kr_off = lane >> 3;               // row-in-group 0..7
    const int k_lc   = (lane & 7) ^ kr_off;     // logical chunk (source swizzle)
    // V staging: wave w, instr i stages e-rows w*16+i*4 .. +3 (4 rows x 16 chunks)
    const int ve_off = lane >> 4;               // 0..3
    const int v_pc   = lane & 15;               // phys chunk
    const size_t vrowbase = (size_t)((b * 16 + h) * 64);

    const int psrow = (w * 16 + ln) * 136;

    for (int kb = 0; kb < SEQ; kb += 128) {
        __syncthreads();              // prev-iter Ks/Vt reads complete
#pragma unroll
        for (int i = 0; i < 4; ++i) {
            const int r = w * 32 + i * 8 + kr_off;
            glds16(K + (size_t)(b * SEQ + kb + r) * DIM + h * HDIM + k_lc * 8,
                   &Ks[(w * 32 + i * 8) * 64]);
        }
#pragma unroll
        for (int i = 0; i < 4; ++i) {
            const int e  = w * 16 + i * 4 + ve_off;
            const int lc = v_pc ^ (i * 4 + ve_off);
            glds16(Vtg + (vrowbase + e) * SEQ + kb + lc * 8,
                   &Vt[(w * 16 + i * 4) * 128]);
        }
        __syncthreads();              // drains vmcnt: tiles visible

        // ---- S^T = K·Q^T for both q-groups; K-frags loaded once
        f32x4 sa0[8], sa1[8];
#pragma unroll
        for (int nt = 0; nt < 8; ++nt) {
            const int rr = (nt * 16 + ln) * 64;
            const bf16x8 kf0 = *(const bf16x8*)&Ks[rr + ((quad ^ (ln & 7)) << 3)];
            const bf16x8 kf1 = *(const bf16x8*)&Ks[rr + (((quad + 4) ^ (ln & 7)) << 3)];
            f32x4 z0 = (f32x4){0.f, 0.f, 0.f, 0.f};
            z0 = MFMA_BF16(kf0, qf[0][0], z0);
            z0 = MFMA_BF16(kf1, qf[0][1], z0);
            sa0[nt] = z0;
            f32x4 z1 = (f32x4){0.f, 0.f, 0.f, 0.f};
            z1 = MFMA_BF16(kf0, qf[1][0], z1);
            z1 = MFMA_BF16(kf1, qf[1][1], z1);
            sa1[nt] = z1;
        }

        // ---- online softmax (scalar state per lane, q = w*16(+16g)+ln)
        float al[2];
#pragma unroll
        for (int g = 0; g < 2; ++g) {
            f32x4* sa = g ? sa1 : sa0;
            float mx = -1e30f;
#pragma unroll
            for (int nt = 0; nt < 8; ++nt)
#pragma unroll
                for (int r = 0; r < 4; ++r) mx = fmaxf(mx, sa[nt][r]);
            mx = fmaxf(mx, __shfl_xor(mx, 16));
            mx = fmaxf(mx, __shfl_xor(mx, 32));
            const float mn = fmaxf(m_s[g], mx);
            al[g] = exp2f(m_s[g] - mn);
            m_s[g] = mn;
            float rs = 0.f;
#pragma unroll
            for (int nt = 0; nt < 8; ++nt)
#pragma unroll
                for (int r = 0; r < 4; ++r) {
                    const float p = exp2f(sa[nt][r] - mn);
                    sa[nt][r] = p;
                    rs += p;
                }
            rs += __shfl_xor(rs, 16);
            rs += __shfl_xor(rs, 32);
            l_s[g] = l_s[g] * al[g] + rs;
#pragma unroll
            for (int r = 0; r < 4; ++r) {
                const float alr = __shfl(al[g], quad * 4 + r);
#pragma unroll
                for (int c = 0; c < 4; ++c) o_acc[g][c][r] *= alr;
            }
        }

        // ---- P g0 -> Ps (wave-private rows)
#pragma unroll
        for (int nt = 0; nt < 8; ++nt) {
            bf16x4 pk = {(bf16)sa0[nt][0], (bf16)sa0[nt][1],
                         (bf16)sa0[nt][2], (bf16)sa0[nt][3]};
            *(bf16x4*)&Ps[psrow + nt * 16 + quad * 4] = pk;
        }
        __asm__ volatile("s_waitcnt lgkmcnt(0)" ::: "memory");
        bf16x8 pf0[4];
#pragma unroll
        for (int kc = 0; kc < 4; ++kc)
            pf0[kc] = *(const bf16x8*)&Ps[psrow + kc * 32 + quad * 8];
        __asm__ volatile("s_waitcnt lgkmcnt(0)" ::: "memory");
        // ---- P g1 -> Ps (same rows)
#pragma unroll
        for (int nt = 0; nt < 8; ++nt) {
            bf16x4 pk = {(bf16)sa1[nt][0], (bf16)sa1[nt][1],
                         (bf16)sa1[nt][2], (bf16)sa1[nt][3]};
            *(bf16x4*)&Ps[psrow + nt * 16 + quad * 4] = pk;
        }
        // ---- V frags (swizzled), loaded once for both groups
        bf16x8 vf[4][4];
#pragma unroll
        for (int kc = 0; kc < 4; ++kc)
#pragma unroll
            for (int c = 0; c < 4; ++c) {
                const int e = c * 16 + ln;
                const int pc = (kc * 4 + quad) ^ ln;
                vf[kc][c] = *(const bf16x8*)&Vt[e * 128 + pc * 8];
            }
        __asm__ volatile("s_waitcnt lgkmcnt(0)" ::: "memory");

#pragma unroll
        for (int kc = 0; kc < 4; ++kc)
#pragma unroll
            for (int c = 0; c < 4; ++c)
                o_acc[0][c] = MFMA_BF16(pf0[kc], vf[kc][c], o_acc[0][c]);
        bf16x8 pf1[4];
#pragma unroll
        for (int kc = 0; kc < 4; ++kc)
            pf1[kc] = *(const bf16x8*)&Ps[psrow + kc * 32 + quad * 8];
        __asm__ volatile("s_waitcnt lgkmcnt(0)" ::: "memory");
#pragma unroll
        for (int kc = 0; kc < 4; ++kc)
#pragma unroll
            for (int c = 0; c < 4; ++c)
                o_acc[1][c] = MFMA_BF16(pf1[kc], vf[kc][c], o_acc[1][c]);
    }

    // ---- epilogue: normalize, store bf16
#pragma unroll
    for (int g = 0; g < 2; ++g) {
        const float linv = 1.0f / l_s[g];
#pragma unroll
        for (int r = 0; r < 4; ++r) {
            const float lr = __shfl(linv, quad * 4 + r);
            const size_t rowoff =
                (size_t)(b * SEQ + q0 + w * 32 + g * 16 + quad * 4 + r) * DIM + h * HDIM;
#pragma unroll
            for (int c = 0; c < 4; ++c)
                O[rowoff + c * 16 + ln] = (bf16)(o_acc[g][c][r] * lr);
        }
    }
}

extern "C" void kernel_launch(void* const* d_in, const int* in_sizes, int n_in,
                              void* d_out, int out_size, void* d_ws, size_t ws_size,
                              hipStream_t stream) {
    // ws: Qb, Kb, Vtg, Ob (bf16, 8 MB each) + flags
    bf16* Qb  = (bf16*)d_ws;
    bf16* Kb  = Qb + (size_t)MROWS * DIM;
    bf16* Vtg = Kb + (size_t)MROWS * DIM;
    bf16* Ob  = Vtg + (size_t)MROWS * DIM;
    int*  flags = (int*)(Ob + (size_t)MROWS * DIM);

    gemm_qkv_kernel<<<dim3(DIM / 128, MROWS / 128, 3), 256, 0, stream>>>(
        d_in[0], d_in[3], d_in[4], Qb,
        d_in[1], d_in[5], d_in[6], Kb,
        d_in[2], d_in[7], d_in[8], Vtg, flags);

    attn_kernel<<<dim3(SEQ / 128, BATCH * 16), 256, 0, stream>>>(Qb, Kb, Vtg, Ob);

    gemm_out_kernel<<<dim3(DIM / 128, MROWS / 128), 256, 0, stream>>>(
        Ob, d_in[9], d_in[10], d_out, flags);
}